// Round 6
// baseline (666.200 us; speedup 1.0000x reference)
//
#include <hip/hip_runtime.h>

typedef _Float16 f16;
typedef _Float16 f16x8 __attribute__((ext_vector_type(8)));
typedef float f32x16 __attribute__((ext_vector_type(16)));

// ---------------------------------------------------------------------------
// async 16B global->LDS copy (global_load_lds_dwordx4)
// LDS side is HW-forced to wave-uniform-base + lane*16 (m104/m108).
// ---------------------------------------------------------------------------
__device__ __forceinline__ void g2lds16(const void* g, void* l) {
    __builtin_amdgcn_global_load_lds(
        (const __attribute__((address_space(1))) void*)g,
        (__attribute__((address_space(3))) void*)l, 16, 0, 0);
}

// ---------------------------------------------------------------------------
// Pack Wq|Wk|Wv -> f16 Wall[2048][1024], biases -> ball[2048] fp32
// ---------------------------------------------------------------------------
__global__ __launch_bounds__(256)
void prep_w(const float* __restrict__ Wq, const float* __restrict__ bq,
            const float* __restrict__ Wk, const float* __restrict__ bk,
            const float* __restrict__ Wv, const float* __restrict__ bv,
            f16* __restrict__ Wall, float* __restrict__ ball)
{
    const int idx = blockIdx.x * 256 + threadIdx.x;   // 0 .. 2^21-1
    const int o = idx >> 10;
    const int c = idx & 1023;
    float w;
    if (o < 512)        w = Wq[idx];
    else if (o < 1024)  w = Wk[idx - 512 * 1024];
    else                w = Wv[idx - 1024 * 1024];
    Wall[idx] = (f16)w;
    if (c == 0)
        ball[o] = (o < 512) ? bq[o] : (o < 1024) ? bk[o - 512] : bv[o - 1024];
}

// ---------------------------------------------------------------------------
// x [B,C,N] fp32 -> xT [B,N,C] f16.  64x64 tile: float4 loads (256B rows),
// f16x8 (16B) stores. LDS pad 65 -> conflict-free.
// ---------------------------------------------------------------------------
__global__ __launch_bounds__(256)
void transpose_cast(const float* __restrict__ x, f16* __restrict__ xT)
{
    __shared__ float t[64][65];
    const int b  = blockIdx.z;
    const int c0 = blockIdx.y << 6;
    const int n0 = blockIdx.x << 6;
    const int tid = threadIdx.x;
    const float* xb = x + (unsigned long long)b * (1024ull * 1024ull);

    {
        const int cl = tid >> 4;          // 0..15
        const int n4 = (tid & 15) << 2;   // 0..60
#pragma unroll
        for (int i = 0; i < 64; i += 16) {
            const float4 v = *(const float4*)(xb + (unsigned long long)(c0 + cl + i) * 1024ull + (n0 + n4));
            t[cl + i][n4 + 0] = v.x; t[cl + i][n4 + 1] = v.y;
            t[cl + i][n4 + 2] = v.z; t[cl + i][n4 + 3] = v.w;
        }
    }
    __syncthreads();
    {
        f16* ob = xT + (unsigned long long)b * (1024ull * 1024ull);
        const int nl = tid >> 3;          // 0..31
        const int c8 = (tid & 7) << 3;    // 0..56
#pragma unroll
        for (int i = 0; i < 64; i += 32) {
            f16x8 h;
#pragma unroll
            for (int j = 0; j < 8; ++j) h[j] = (f16)t[c8 + j][nl + i];
            *(f16x8*)(ob + (unsigned long long)(n0 + nl + i) * 1024ull + (c0 + c8)) = h;
        }
    }
}

// ---------------------------------------------------------------------------
// NT GEMM: C[m,n] = sum_k A[m,k]*B[n,k]  (both row-major, contract last dim)
// 128x128 tile, BK=64, 4 waves 2x2, 64x64/wave, mfma_f32_32x32x16_f16 (2x2).
// LDS: flat [128][64] f16, XOR-swizzled on the GLOBAL address side.
// SWZ=1 (GEMM1): XCD-pinned supertiles (see prior notes; 3MB < 4MB L2).
// SWZ=2 (GEMM3): 1-D grid 2048; pin (batch, bn-half) units to XCDs:
//   per unit working set = A (V, 2MB) + B-half (P, 1MB) = 3MB < 4MB L2.
// EPI 0: +bias[n] store f16. EPI 1: store fp32. EPI 2: +=Xres store fp32.
// ---------------------------------------------------------------------------
template <int EPI, int LDA, int LDB, int K, int LDO,
          long long SA, long long SB, long long SO, int SWZ>
__global__ __launch_bounds__(256, 4)
void gemm_nt(const f16* __restrict__ A, const f16* __restrict__ Bm,
             const float* __restrict__ bias,
             f16* __restrict__ Oh, float* __restrict__ Of,
             const float* __restrict__ Xres)
{
    __shared__ f16 As[128 * 64];
    __shared__ f16 Bs[128 * 64];

    const int tid  = threadIdx.x;
    const int wave = tid >> 6;
    const int lane = tid & 63;
    const int l31  = lane & 31;
    const int half = lane >> 5;
    const int wr   = (wave >> 1) << 6;   // wave row offset: 0 / 64
    const int wc   = (wave & 1) << 6;    // wave col offset: 0 / 64

    int bm, bn, bz = blockIdx.z;
    if (SWZ == 1) {
        const int xcd   = blockIdx.x & 7;
        const int local = blockIdx.x >> 3;    // 0..511
        const int stl   = local >> 5;         // 0..15 sequential per XCD
        const int sub   = local & 31;
        const int bng   = xcd & 1;            // bn-half owned by this XCD
        const int g4    = stl * 4 + (xcd >> 1);  // 0..63 bm-group-of-4
        bm = (g4 * 4 + (sub & 3)) << 7;
        bn = (bng * 8 + (sub >> 2)) << 7;
    } else if (SWZ == 2) {
        const int xcd   = blockIdx.x & 7;
        const int local = blockIdx.x >> 3;    // 0..255
        const int unit  = local >> 5;         // 0..7 sequential per XCD
        const int wi    = local & 31;         // 8 bm x 4 bn-within-half
        const int pp    = unit * 8 + xcd;     // 0..63 (batch, half) pairs
        bz = pp >> 1;
        const int bh = pp & 1;
        bm = (wi & 7) << 7;
        bn = ((bh << 2) + (wi >> 3)) << 7;
    } else {
        bm = blockIdx.x << 7;
        bn = blockIdx.y << 7;
    }

    const f16* Ab = A  + (unsigned long long)bz * (unsigned long long)SA;
    const f16* Bb = Bm + (unsigned long long)bz * (unsigned long long)SB;

    // staging: lane -> row rb + (l>>3); global k-group XOR-swizzled
    const int srow = lane >> 3;                    // 0..7
    const int scol = (((lane & 7) ^ srow) << 3);   // swizzled f16 col offset

    f32x16 acc[2][2] = {};

    for (int k0 = 0; k0 < K; k0 += 64) {
        __syncthreads();
#pragma unroll
        for (int t = 0; t < 4; ++t) {
            const int rb = t * 32 + wave * 8;     // wave-uniform
            g2lds16(Ab + (unsigned long long)(bm + rb + srow) * LDA + (k0 + scol),
                    As + rb * 64 + lane * 8);
            g2lds16(Bb + (unsigned long long)(bn + rb + srow) * LDB + (k0 + scol),
                    Bs + rb * 64 + lane * 8);
        }
        __syncthreads();

#pragma unroll
        for (int ks = 0; ks < 4; ++ks) {
            const int kg = ks * 2 + half;         // k-group 0..7
            f16x8 af[2], bf[2];
#pragma unroll
            for (int i = 0; i < 2; ++i) {
                const int ra = wr + i * 32 + l31;
                af[i] = *(const f16x8*)(As + ra * 64 + ((kg ^ (ra & 7)) << 3));
                const int rbn = wc + i * 32 + l31;
                bf[i] = *(const f16x8*)(Bs + rbn * 64 + ((kg ^ (rbn & 7)) << 3));
            }
#pragma unroll
            for (int mi = 0; mi < 2; ++mi)
#pragma unroll
                for (int ni = 0; ni < 2; ++ni)
                    acc[mi][ni] = __builtin_amdgcn_mfma_f32_32x32x16_f16(
                        af[mi], bf[ni], acc[mi][ni], 0, 0, 0);
        }
    }

    // epilogue: 32x32 C/D layout col=lane&31, row=(r&3)+8*(r>>2)+4*half
#pragma unroll
    for (int mi = 0; mi < 2; ++mi) {
#pragma unroll
        for (int ni = 0; ni < 2; ++ni) {
            const int col = bn + wc + ni * 32 + l31;
            float bc = 0.0f;
            if (EPI == 0) bc = bias[col];
#pragma unroll
            for (int r = 0; r < 16; ++r) {
                const int row = bm + wr + mi * 32 + (r & 3) + 8 * (r >> 2) + 4 * half;
                const float val = acc[mi][ni][r];
                if (EPI == 0) {
                    Oh[(unsigned long long)row * LDO + col] = (f16)(val + bc);
                } else if (EPI == 1) {
                    Of[(unsigned long long)bz * (unsigned long long)SO +
                       (unsigned long long)row * LDO + col] = val;
                } else {
                    const unsigned long long off =
                        (unsigned long long)bz * (unsigned long long)SO +
                        (unsigned long long)row * LDO + col;
                    Of[off] = val + Xres[off];
                }
            }
        }
    }
}

// ---------------------------------------------------------------------------
// Fused scores + row-softmax v3:  P[b,j,key] = softmax_key(Q[b,j,:].K[b,key,:])
// Block = one batch x 32 q-rows x 1024 keys; 8 waves, wave w owns keys
// [128w,128w+128).  NO LDS in the K-loop: Q and K fragments are per-lane
// addressable (af = Q[j0+l31][k], bf = K[key0+l31][k]) -> direct-to-register
// global loads from L2 (T14), 2-deep static double-buffer (rule 20: all
// indices compile-time after unroll).  Compiler emits counted waitcnts.
// LDS only for P repack + reduce (68KB) -> 2 blocks/CU, 4 waves/SIMD (TLP).
// __launch_bounds__(512,4): cap 128 VGPR (acc 64 + kbuf 32 + qbuf 8 + addr).
// Softmax: butterfly over l31 + 8-wave LDS reduce (v1-verified epilogue).
// XCD-pinned: batch = xcd*4+..., K+Q L2-resident per XCD.
// ---------------------------------------------------------------------------
__global__ __launch_bounds__(512, 4)
void qk_softmax(const f16* __restrict__ QKV, f16* __restrict__ P)
{
    __shared__ f16 Pt[32 * 1024];           // 64KB P repack tile
    __shared__ float redm[8][2][16];        // 2KB [wave][half][r]
    __shared__ float reds[8][2][16];        // 2KB

    const int tid  = threadIdx.x;
    const int wave = tid >> 6;
    const int lane = tid & 63;
    const int l31  = lane & 31;
    const int half = lane >> 5;

    const int xcd   = blockIdx.x & 7;
    const int local = blockIdx.x >> 3;          // 0..127
    const int batch = xcd * 4 + (local >> 5);   // 4 batches per XCD
    const int j0    = (local & 31) << 5;        // 32-row q tile

    const f16* Qb = QKV + (unsigned long long)batch * (1024ull * 2048ull);
    const f16* Kb = Qb + 512;

    // per-lane fragment source rows (16B-aligned: k offsets are mult of 8 f16)
    const f16* Qrow = Qb + (unsigned long long)(j0 + l31) * 2048ull + half * 8;
    const f16* Kp0  = Kb + (unsigned long long)(wave * 128 + l31) * 2048ull + half * 8;
    const f16* Kp1  = Kp0 + 32ull * 2048ull;
    const f16* Kp2  = Kp0 + 64ull * 2048ull;
    const f16* Kp3  = Kp0 + 96ull * 2048ull;

    f32x16 acc[4] = {};
    f16x8 qb_[2], kb0[2], kb1[2], kb2[2], kb3[2];

    // prefetch chunks 0,1 (each chunk = 16 d; lane covers half*8..+8)
#pragma unroll
    for (int i = 0; i < 2; ++i) {
        qb_[i] = *(const f16x8*)(Qrow + i * 16);
        kb0[i] = *(const f16x8*)(Kp0 + i * 16);
        kb1[i] = *(const f16x8*)(Kp1 + i * 16);
        kb2[i] = *(const f16x8*)(Kp2 + i * 16);
        kb3[i] = *(const f16x8*)(Kp3 + i * 16);
    }

    for (int tt = 0; tt < 16; ++tt) {
#pragma unroll
        for (int p = 0; p < 2; ++p) {           // buffer parity compile-time
            const int t = tt * 2 + p;           // chunk 0..31
            acc[0] = __builtin_amdgcn_mfma_f32_32x32x16_f16(qb_[p], kb0[p], acc[0], 0, 0, 0);
            acc[1] = __builtin_amdgcn_mfma_f32_32x32x16_f16(qb_[p], kb1[p], acc[1], 0, 0, 0);
            acc[2] = __builtin_amdgcn_mfma_f32_32x32x16_f16(qb_[p], kb2[p], acc[2], 0, 0, 0);
            acc[3] = __builtin_amdgcn_mfma_f32_32x32x16_f16(qb_[p], kb3[p], acc[3], 0, 0, 0);
            if (t + 2 < 32) {                   // uniform branch; WAR on bufs
                const int off = (t + 2) * 16;
                qb_[p] = *(const f16x8*)(Qrow + off);
                kb0[p] = *(const f16x8*)(Kp0 + off);
                kb1[p] = *(const f16x8*)(Kp1 + off);
                kb2[p] = *(const f16x8*)(Kp2 + off);
                kb3[p] = *(const f16x8*)(Kp3 + off);
            }
        }
    }

    // ---- row softmax over 1024 keys (v1-verified epilogue) ----
    float mx[16];
#pragma unroll
    for (int r = 0; r < 16; ++r) {
        float m = fmaxf(fmaxf(acc[0][r], acc[1][r]), fmaxf(acc[2][r], acc[3][r]));
#pragma unroll
        for (int off = 16; off; off >>= 1)
            m = fmaxf(m, __shfl_xor(m, off, 64));
        mx[r] = m;
    }
    if (l31 == 0) {
#pragma unroll
        for (int r = 0; r < 16; ++r) redm[wave][half][r] = mx[r];
    }
    __syncthreads();
#pragma unroll
    for (int r = 0; r < 16; ++r) {
        float m = redm[0][half][r];
#pragma unroll
        for (int w = 1; w < 8; ++w) m = fmaxf(m, redm[w][half][r]);
        mx[r] = m;
    }

    float sm[16];
#pragma unroll
    for (int r = 0; r < 16; ++r) sm[r] = 0.0f;
#pragma unroll
    for (int ni = 0; ni < 4; ++ni)
#pragma unroll
        for (int r = 0; r < 16; ++r) {
            const float e = __expf(acc[ni][r] - mx[r]);
            acc[ni][r] = e;
            sm[r] += e;
        }
#pragma unroll
    for (int r = 0; r < 16; ++r) {
#pragma unroll
        for (int off = 16; off; off >>= 1)
            sm[r] += __shfl_xor(sm[r], off, 64);
    }
    if (l31 == 0) {
#pragma unroll
        for (int r = 0; r < 16; ++r) reds[wave][half][r] = sm[r];
    }
    __syncthreads();
#pragma unroll
    for (int r = 0; r < 16; ++r) {
        float s = reds[0][half][r];
#pragma unroll
        for (int w = 1; w < 8; ++w) s += reds[w][half][r];
        sm[r] = 1.0f / s;
    }

    // ---- write P tile through LDS -> coalesced 16B stores ----
    const int wkey = wave << 7;
#pragma unroll
    for (int ni = 0; ni < 4; ++ni)
#pragma unroll
        for (int r = 0; r < 16; ++r) {
            const int row = (r & 3) + 8 * (r >> 2) + 4 * half;
            const int key = wkey + ni * 32 + l31;
            Pt[row * 1024 + key] = (f16)(acc[ni][r] * sm[r]);
        }
    __syncthreads();

    // tile is 32 contiguous rows -> flat contiguous 64KB copy, 16B per lane
    f16* Pg = P + ((unsigned long long)batch * 1024ull + j0) * 1024ull;
#pragma unroll
    for (int i = 0; i < 8; ++i)
        *(f16x8*)(Pg + i * 4096 + tid * 8) = *(const f16x8*)(Pt + i * 4096 + tid * 8);
}

// ---------------------------------------------------------------------------
extern "C" void kernel_launch(void* const* d_in, const int* in_sizes, int n_in,
                              void* d_out, int out_size, void* d_ws, size_t ws_size,
                              hipStream_t stream)
{
    const float* x  = (const float*)d_in[0];
    const float* Wq = (const float*)d_in[1];
    const float* bq = (const float*)d_in[2];
    const float* Wk = (const float*)d_in[3];
    const float* bk = (const float*)d_in[4];
    const float* Wv = (const float*)d_in[5];
    const float* bv = (const float*)d_in[6];
    float* out = (float*)d_out;

    // workspace layout (all 16B-aligned)
    f16*   xT   = (f16*)d_ws;                               //  64 MB: [32,1024(N),1024(C)]
    f16*   Wall = xT + 32ull * 1024 * 1024;                 //   4 MB: [2048,1024]
    float* ball = (float*)(Wall + 2048ull * 1024);          //   8 KB
    f16*   QKV  = (f16*)(ball + 2048);                      // 128 MB: [32,1024, q|k|v 2048]
    f16*   P    = QKV + 64ull * 1024 * 1024;                //  64 MB: [32,1024,1024]

    prep_w<<<8192, 256, 0, stream>>>(Wq, bq, Wk, bk, Wv, bv, Wall, ball);
    transpose_cast<<<dim3(16, 16, 32), 256, 0, stream>>>(x, xT);

    // QKV projection: [32768,1024] x [2048,1024]^T -> [32768,2048], +bias, f16
    gemm_nt<0, 1024, 1024, 1024, 2048, 0ll, 0ll, 0ll, 1>
        <<<dim3(4096, 1, 1), 256, 0, stream>>>(
        xT, Wall, ball, QKV, nullptr, nullptr);

    // fused scores + softmax: per batch q[1024,512] x k'[1024,512]^T -> P f16
    qk_softmax<<<dim3(1024, 1, 1), 512, 0, stream>>>(QKV, P);

    // out: per batch  v[1024,1024] x attn[1024,1024]^T  (+x residual) -> fp32
    gemm_nt<2, 2048, 1024, 1024, 1024, 1024ll * 2048, 1024ll * 1024, 1024ll * 1024, 2>
        <<<dim3(2048, 1, 1), 256, 0, stream>>>(
        QKV + 1024, P, nullptr, nullptr, out, x);
}